// Round 1
// baseline (1601.761 us; speedup 1.0000x reference)
//
#include <hip/hip_runtime.h>

#define B_ 8
#define N_ 4096
#define V_ 1024
#define KQ_ 256
#define KQOFF 768

// ---------------------------------------------------------------------------
// ws layout (floats):
//   S  [8][256][256]    @ 0          (zeroed, atomic-accumulated)
//   s  [8][256]         @ 524288     (zeroed, atomic-accumulated)
//   T  [8][1024][256]   @ 526336     T_b = Wk @ S_b
//   u  [8][1024]        @ 2623488    u_b = Wq s_b
//   t  [8][1024]        @ 2631680    t_b = Wk s_b
//   L  [8][1024][1024]  @ 2639872    logits -> attn (softmaxed in place)
//   C  [8][1024][1024]  @ 11028480   C_b = Wv^T attn_b
//   c  [8][1024]        @ 19417088   c_b = attn_b^T bv
// total 19425280 floats = 77.7 MB
// ---------------------------------------------------------------------------

// s_b[k] = sum_n input[b,n,768+k]
__global__ void k_sum_s(const float* __restrict__ in, float* __restrict__ s) {
    const int b = blockIdx.x, chunk = blockIdx.y, k = threadIdx.x;
    const float* p = in + ((size_t)b * N_ + (size_t)chunk * 256) * V_ + KQOFF + k;
    float acc = 0.f;
    for (int r = 0; r < 256; ++r) acc += p[(size_t)r * V_];
    atomicAdd(&s[b * KQ_ + k], acc);
}

// S_b[i,j] = sum_n X[n,i]*X[n,j],  X[n,k] = input[b,n,768+k]
__global__ void k_syrk(const float* __restrict__ in, float* __restrict__ S) {
    const int bz = blockIdx.z;          // b*8 + nchunk
    const int b = bz >> 3, nc = bz & 7;
    const int i0 = blockIdx.x * 64, j0 = blockIdx.y * 64;
    __shared__ float As[16][64], Bs[16][64];
    const int tid = threadIdx.x, tx = tid & 15, ty = tid >> 4;
    const int lrow = tid >> 4, lcol = (tid & 15) * 4;
    float acc[4][4] = {};
    const float* Xb = in + (size_t)b * N_ * V_ + KQOFF;
    const int nbeg = nc * 512, nend = nbeg + 512;
    for (int n0 = nbeg; n0 < nend; n0 += 16) {
        const float* base = Xb + (size_t)(n0 + lrow) * V_;
        const float4 a4 = *(const float4*)(base + i0 + lcol);
        const float4 b4 = *(const float4*)(base + j0 + lcol);
        *(float4*)&As[lrow][lcol] = a4;
        *(float4*)&Bs[lrow][lcol] = b4;
        __syncthreads();
#pragma unroll
        for (int kk = 0; kk < 16; ++kk) {
            float ra[4], rb[4];
#pragma unroll
            for (int a = 0; a < 4; ++a) ra[a] = As[kk][ty * 4 + a];
#pragma unroll
            for (int q = 0; q < 4; ++q) rb[q] = Bs[kk][tx * 4 + q];
#pragma unroll
            for (int a = 0; a < 4; ++a)
#pragma unroll
                for (int q = 0; q < 4; ++q) acc[a][q] += ra[a] * rb[q];
        }
        __syncthreads();
    }
#pragma unroll
    for (int a = 0; a < 4; ++a)
#pragma unroll
        for (int q = 0; q < 4; ++q)
            atomicAdd(&S[((size_t)b * KQ_ + i0 + ty * 4 + a) * KQ_ + j0 + tx * 4 + q],
                      acc[a][q]);
}

// u_b = Wq s_b ; t_b = Wk s_b
__global__ void k_uv(const float* __restrict__ Wq, const float* __restrict__ Wk,
                     const float* __restrict__ s, float* __restrict__ u,
                     float* __restrict__ t) {
    const int b = blockIdx.x;
    const int w = blockIdx.y * 256 + threadIdx.x;
    __shared__ float sl[256];
    sl[threadIdx.x] = s[b * KQ_ + threadIdx.x];
    __syncthreads();
    float au = 0.f, at = 0.f;
    const float* qr = Wq + (size_t)w * KQ_;
    const float* kr = Wk + (size_t)w * KQ_;
    for (int i = 0; i < KQ_; ++i) { au += qr[i] * sl[i]; at += kr[i] * sl[i]; }
    u[b * V_ + w] = au;
    t[b * V_ + w] = at;
}

// T_b = Wk @ S_b   (M=1024, N=256, K=256)
__global__ void k_wkS(const float* __restrict__ Wk, const float* __restrict__ S,
                      float* __restrict__ T) {
    const int b = blockIdx.z;
    const int i0 = blockIdx.x * 64, j0 = blockIdx.y * 64;
    __shared__ float As[64][17];
    __shared__ float Bs[16][64];
    const int tid = threadIdx.x, tx = tid & 15, ty = tid >> 4;
    const int ar = tid >> 2, ac = (tid & 3) * 4;
    const int br = tid >> 4, bc = (tid & 15) * 4;
    float acc[4][4] = {};
    for (int k0 = 0; k0 < KQ_; k0 += 16) {
        const float4 a4 = *(const float4*)(Wk + (size_t)(i0 + ar) * KQ_ + k0 + ac);
        As[ar][ac + 0] = a4.x; As[ar][ac + 1] = a4.y;
        As[ar][ac + 2] = a4.z; As[ar][ac + 3] = a4.w;
        const float4 b4 = *(const float4*)(S + ((size_t)b * KQ_ + k0 + br) * KQ_ + j0 + bc);
        *(float4*)&Bs[br][bc] = b4;
        __syncthreads();
#pragma unroll
        for (int kk = 0; kk < 16; ++kk) {
            float ra[4], rb[4];
#pragma unroll
            for (int a = 0; a < 4; ++a) ra[a] = As[ty * 4 + a][kk];
#pragma unroll
            for (int q = 0; q < 4; ++q) rb[q] = Bs[kk][tx * 4 + q];
#pragma unroll
            for (int a = 0; a < 4; ++a)
#pragma unroll
                for (int q = 0; q < 4; ++q) acc[a][q] += ra[a] * rb[q];
        }
        __syncthreads();
    }
#pragma unroll
    for (int a = 0; a < 4; ++a) {
        float4 o; o.x = acc[a][0]; o.y = acc[a][1]; o.z = acc[a][2]; o.w = acc[a][3];
        *(float4*)(T + ((size_t)b * V_ + i0 + ty * 4 + a) * KQ_ + j0 + tx * 4) = o;
    }
}

// L_b[v,w] = sum_k T_b[v,k]*Wq[w,k] + bk[v]*(u[b,w] + N*bq[w]) + t[b,v]*bq[w]
__global__ void k_logits(const float* __restrict__ T, const float* __restrict__ Wq,
                         const float* __restrict__ bk, const float* __restrict__ bq,
                         const float* __restrict__ u, const float* __restrict__ t,
                         float* __restrict__ L) {
    const int b = blockIdx.z;
    const int i0 = blockIdx.x * 64, j0 = blockIdx.y * 64;
    __shared__ float As[64][17], Bs[64][17];
    const int tid = threadIdx.x, tx = tid & 15, ty = tid >> 4;
    const int r = tid >> 2, c = (tid & 3) * 4;
    float acc[4][4] = {};
    for (int k0 = 0; k0 < KQ_; k0 += 16) {
        const float4 a4 = *(const float4*)(T + ((size_t)b * V_ + i0 + r) * KQ_ + k0 + c);
        As[r][c + 0] = a4.x; As[r][c + 1] = a4.y; As[r][c + 2] = a4.z; As[r][c + 3] = a4.w;
        const float4 b4 = *(const float4*)(Wq + (size_t)(j0 + r) * KQ_ + k0 + c);
        Bs[r][c + 0] = b4.x; Bs[r][c + 1] = b4.y; Bs[r][c + 2] = b4.z; Bs[r][c + 3] = b4.w;
        __syncthreads();
#pragma unroll
        for (int kk = 0; kk < 16; ++kk) {
            float ra[4], rb[4];
#pragma unroll
            for (int a = 0; a < 4; ++a) ra[a] = As[ty * 4 + a][kk];
#pragma unroll
            for (int q = 0; q < 4; ++q) rb[q] = Bs[tx * 4 + q][kk];
#pragma unroll
            for (int a = 0; a < 4; ++a)
#pragma unroll
                for (int q = 0; q < 4; ++q) acc[a][q] += ra[a] * rb[q];
        }
        __syncthreads();
    }
#pragma unroll
    for (int a = 0; a < 4; ++a) {
        const int v = i0 + ty * 4 + a;
        const float bkv = bk[v];
        const float tv = t[b * V_ + v];
        float4 o;
        float* po = (float*)&o;
#pragma unroll
        for (int q = 0; q < 4; ++q) {
            const int w = j0 + tx * 4 + q;
            po[q] = acc[a][q] + bkv * (u[b * V_ + w] + 4096.0f * bq[w]) + tv * bq[w];
        }
        *(float4*)(L + ((size_t)b * V_ + v) * V_ + j0 + tx * 4) = o;
    }
}

// row-wise softmax over w (rows of 1024)
__global__ void k_softmax(float* __restrict__ L) {
    const size_t row = blockIdx.x;
    float* p = L + row * V_;
    const int t = threadIdx.x;
    float vals[4];
    float m = -3.4e38f;
#pragma unroll
    for (int i = 0; i < 4; ++i) { vals[i] = p[t + i * 256]; m = fmaxf(m, vals[i]); }
    __shared__ float red[256];
    red[t] = m; __syncthreads();
    for (int s2 = 128; s2 > 0; s2 >>= 1) {
        if (t < s2) red[t] = fmaxf(red[t], red[t + s2]);
        __syncthreads();
    }
    m = red[0]; __syncthreads();
    float sum = 0.f;
#pragma unroll
    for (int i = 0; i < 4; ++i) { vals[i] = __expf(vals[i] - m); sum += vals[i]; }
    red[t] = sum; __syncthreads();
    for (int s2 = 128; s2 > 0; s2 >>= 1) {
        if (t < s2) red[t] += red[t + s2];
        __syncthreads();
    }
    const float inv = 1.f / red[0];
#pragma unroll
    for (int i = 0; i < 4; ++i) p[t + i * 256] = vals[i] * inv;
}

// C_b[e,w] = sum_v Wv[v,e] * attn_b[v,w]   (TN, M=N=K=1024)
__global__ void k_C(const float* __restrict__ Wv, const float* __restrict__ L,
                    float* __restrict__ C) {
    const int b = blockIdx.z;
    const int i0 = blockIdx.x * 64, j0 = blockIdx.y * 64;
    __shared__ float As[16][64], Bs[16][64];
    const int tid = threadIdx.x, tx = tid & 15, ty = tid >> 4;
    const int lrow = tid >> 4, lcol = (tid & 15) * 4;
    float acc[4][4] = {};
    const float* Lb = L + (size_t)b * V_ * V_;
    for (int k0 = 0; k0 < V_; k0 += 16) {
        const float4 a4 = *(const float4*)(Wv + (size_t)(k0 + lrow) * V_ + i0 + lcol);
        const float4 b4 = *(const float4*)(Lb + (size_t)(k0 + lrow) * V_ + j0 + lcol);
        *(float4*)&As[lrow][lcol] = a4;
        *(float4*)&Bs[lrow][lcol] = b4;
        __syncthreads();
#pragma unroll
        for (int kk = 0; kk < 16; ++kk) {
            float ra[4], rb[4];
#pragma unroll
            for (int a = 0; a < 4; ++a) ra[a] = As[kk][ty * 4 + a];
#pragma unroll
            for (int q = 0; q < 4; ++q) rb[q] = Bs[kk][tx * 4 + q];
#pragma unroll
            for (int a = 0; a < 4; ++a)
#pragma unroll
                for (int q = 0; q < 4; ++q) acc[a][q] += ra[a] * rb[q];
        }
        __syncthreads();
    }
#pragma unroll
    for (int a = 0; a < 4; ++a) {
        float4 o; o.x = acc[a][0]; o.y = acc[a][1]; o.z = acc[a][2]; o.w = acc[a][3];
        *(float4*)(C + ((size_t)b * V_ + i0 + ty * 4 + a) * V_ + j0 + tx * 4) = o;
    }
}

// c_b[w] = sum_v bv[v] * attn_b[v,w]
__global__ void k_cvec(const float* __restrict__ bv, const float* __restrict__ L,
                       float* __restrict__ c) {
    const int b = blockIdx.x;
    const int w = blockIdx.y * 256 + threadIdx.x;
    const float* p = L + (size_t)b * V_ * V_ + w;
    float acc = 0.f;
    for (int v = 0; v < V_; ++v) acc += bv[v] * p[(size_t)v * V_];
    c[b * V_ + w] = acc;
}

// out[b,n,w] = gamma*( input[b,n,:]·C_b[:,w] + c_b[w] ) + input[b,n,w]
__global__ void k_out(const float* __restrict__ in, const float* __restrict__ C,
                      const float* __restrict__ cvec, const float* __restrict__ gamma,
                      float* __restrict__ out) {
    const int b = blockIdx.z;
    const int i0 = blockIdx.x * 64;  // n tile
    const int j0 = blockIdx.y * 64;  // w tile
    __shared__ float As[64][17];
    __shared__ float Bs[16][64];
    const int tid = threadIdx.x, tx = tid & 15, ty = tid >> 4;
    const int ar = tid >> 2, ac = (tid & 3) * 4;
    const int br = tid >> 4, bc = (tid & 15) * 4;
    float acc[4][4] = {};
    const float* Ab = in + ((size_t)b * N_ + i0) * V_;
    const float* Bb = C + (size_t)b * V_ * V_;
    for (int k0 = 0; k0 < V_; k0 += 16) {
        const float4 a4 = *(const float4*)(Ab + (size_t)ar * V_ + k0 + ac);
        As[ar][ac + 0] = a4.x; As[ar][ac + 1] = a4.y;
        As[ar][ac + 2] = a4.z; As[ar][ac + 3] = a4.w;
        const float4 b4 = *(const float4*)(Bb + (size_t)(k0 + br) * V_ + j0 + bc);
        *(float4*)&Bs[br][bc] = b4;
        __syncthreads();
#pragma unroll
        for (int kk = 0; kk < 16; ++kk) {
            float ra[4], rb[4];
#pragma unroll
            for (int a = 0; a < 4; ++a) ra[a] = As[ty * 4 + a][kk];
#pragma unroll
            for (int q = 0; q < 4; ++q) rb[q] = Bs[kk][tx * 4 + q];
#pragma unroll
            for (int a = 0; a < 4; ++a)
#pragma unroll
                for (int q = 0; q < 4; ++q) acc[a][q] += ra[a] * rb[q];
        }
        __syncthreads();
    }
    const float g = gamma[0];
    const float4 cv = *(const float4*)(cvec + b * V_ + j0 + tx * 4);
#pragma unroll
    for (int a = 0; a < 4; ++a) {
        const int n = i0 + ty * 4 + a;
        const float4 r4 = *(const float4*)(in + ((size_t)b * N_ + n) * V_ + j0 + tx * 4);
        float4 o;
        o.x = g * (acc[a][0] + cv.x) + r4.x;
        o.y = g * (acc[a][1] + cv.y) + r4.y;
        o.z = g * (acc[a][2] + cv.z) + r4.z;
        o.w = g * (acc[a][3] + cv.w) + r4.w;
        *(float4*)(out + ((size_t)b * N_ + n) * V_ + j0 + tx * 4) = o;
    }
}

extern "C" void kernel_launch(void* const* d_in, const int* in_sizes, int n_in,
                              void* d_out, int out_size, void* d_ws, size_t ws_size,
                              hipStream_t stream) {
    const float* in    = (const float*)d_in[0];
    const float* Wq    = (const float*)d_in[1];
    const float* bq    = (const float*)d_in[2];
    const float* Wk    = (const float*)d_in[3];
    const float* bk    = (const float*)d_in[4];
    const float* Wv    = (const float*)d_in[5];
    const float* bv    = (const float*)d_in[6];
    const float* gamma = (const float*)d_in[7];
    float* out = (float*)d_out;
    float* ws = (float*)d_ws;

    float* S  = ws + 0;
    float* sv = ws + 524288;
    float* T  = ws + 526336;
    float* u  = ws + 2623488;
    float* tt = ws + 2631680;
    float* L  = ws + 2639872;
    float* C  = ws + 11028480;
    float* cv = ws + 19417088;

    // zero the atomic accumulators (S and s are adjacent)
    hipMemsetAsync(S, 0, (size_t)(524288 + 2048) * sizeof(float), stream);

    k_sum_s  <<<dim3(8, 16),    256, 0, stream>>>(in, sv);
    k_syrk   <<<dim3(4, 4, 64), 256, 0, stream>>>(in, S);
    k_uv     <<<dim3(8, 4),     256, 0, stream>>>(Wq, Wk, sv, u, tt);
    k_wkS    <<<dim3(16, 4, 8), 256, 0, stream>>>(Wk, S, T);
    k_logits <<<dim3(16, 16, 8),256, 0, stream>>>(T, Wq, bk, bq, u, tt, L);
    k_softmax<<<8192,           256, 0, stream>>>(L);
    k_C      <<<dim3(16, 16, 8),256, 0, stream>>>(Wv, L, C);
    k_cvec   <<<dim3(8, 4),     256, 0, stream>>>(bv, L, cv);
    k_out    <<<dim3(64, 16, 8),256, 0, stream>>>(in, C, cv, gamma, out);
}

// Round 2
// 668.038 us; speedup vs baseline: 2.3977x; 2.3977x over previous
//
#include <hip/hip_runtime.h>

#define B_ 8
#define N_ 4096
#define V_ 1024
#define KQ_ 256
#define KQOFF 768

typedef unsigned short u16;
typedef unsigned int u32;
typedef __attribute__((ext_vector_type(8))) __bf16 bf16x8;
typedef __attribute__((ext_vector_type(4))) float f32x4;

__device__ __forceinline__ u16 f2bf(float f) {              // RNE
    union { float f; u32 u; } v; v.f = f;
    u32 r = v.u + 0x7fffu + ((v.u >> 16) & 1u);
    return (u16)(r >> 16);
}
__device__ __forceinline__ float bf2f(u16 h) {
    union { u32 u; float f; } v; v.u = ((u32)h) << 16; return v.f;
}
// async global->LDS, 16B per lane; LDS dest must be wave-uniform base + lane*16
__device__ __forceinline__ void gl_lds16(const void* g, void* l) {
    __builtin_amdgcn_global_load_lds((const __attribute__((address_space(1))) u32*)g,
                                     (__attribute__((address_space(3))) u32*)l, 16, 0, 0);
}

// ---------------------------------------------------------------------------
// ws layout (float slots):
//   S  [8][256][256]      @ 0          (zeroed, atomic-accum; WvT_bf16 aliases after k_wkS)
//   s  [8][256]           @ 524288
//   T  [8][1024][256]     @ 526336
//   u  [8][1024]          @ 2623488
//   t  [8][1024]          @ 2631680
//   L  [8][1024][1024]    @ 2639872    logits -> attn fp32 (softmax in place)
//   attnT bf16 [8][w][v]  @ 11028480   (4194304 slots)
//   Ct    bf16 [8][w][e]  @ 15222784   (4194304 slots)
//   c  [8][1024]          @ 19417088
// total 19425280 floats = 77.7 MB (same as round 1)
// ---------------------------------------------------------------------------

__global__ void k_sum_s(const float* __restrict__ in, float* __restrict__ s) {
    const int b = blockIdx.x, chunk = blockIdx.y, k = threadIdx.x;
    const float* p = in + ((size_t)b * N_ + (size_t)chunk * 256) * V_ + KQOFF + k;
    float acc = 0.f;
    for (int r = 0; r < 256; ++r) acc += p[(size_t)r * V_];
    atomicAdd(&s[b * KQ_ + k], acc);
}

__global__ void k_syrk(const float* __restrict__ in, float* __restrict__ S) {
    const int bz = blockIdx.z;
    const int b = bz >> 3, nc = bz & 7;
    const int i0 = blockIdx.x * 64, j0 = blockIdx.y * 64;
    __shared__ float As[16][64], Bs[16][64];
    const int tid = threadIdx.x, tx = tid & 15, ty = tid >> 4;
    const int lrow = tid >> 4, lcol = (tid & 15) * 4;
    float acc[4][4] = {};
    const float* Xb = in + (size_t)b * N_ * V_ + KQOFF;
    const int nbeg = nc * 512, nend = nbeg + 512;
    for (int n0 = nbeg; n0 < nend; n0 += 16) {
        const float* base = Xb + (size_t)(n0 + lrow) * V_;
        const float4 a4 = *(const float4*)(base + i0 + lcol);
        const float4 b4 = *(const float4*)(base + j0 + lcol);
        *(float4*)&As[lrow][lcol] = a4;
        *(float4*)&Bs[lrow][lcol] = b4;
        __syncthreads();
#pragma unroll
        for (int kk = 0; kk < 16; ++kk) {
            float ra[4], rb[4];
#pragma unroll
            for (int a = 0; a < 4; ++a) ra[a] = As[kk][ty * 4 + a];
#pragma unroll
            for (int q = 0; q < 4; ++q) rb[q] = Bs[kk][tx * 4 + q];
#pragma unroll
            for (int a = 0; a < 4; ++a)
#pragma unroll
                for (int q = 0; q < 4; ++q) acc[a][q] += ra[a] * rb[q];
        }
        __syncthreads();
    }
#pragma unroll
    for (int a = 0; a < 4; ++a)
#pragma unroll
        for (int q = 0; q < 4; ++q)
            atomicAdd(&S[((size_t)b * KQ_ + i0 + ty * 4 + a) * KQ_ + j0 + tx * 4 + q],
                      acc[a][q]);
}

__global__ void k_uv(const float* __restrict__ Wq, const float* __restrict__ Wk,
                     const float* __restrict__ s, float* __restrict__ u,
                     float* __restrict__ t) {
    const int b = blockIdx.x;
    const int w = blockIdx.y * 256 + threadIdx.x;
    __shared__ float sl[256];
    sl[threadIdx.x] = s[b * KQ_ + threadIdx.x];
    __syncthreads();
    float au = 0.f, at = 0.f;
    const float* qr = Wq + (size_t)w * KQ_;
    const float* kr = Wk + (size_t)w * KQ_;
    for (int i = 0; i < KQ_; ++i) { au += qr[i] * sl[i]; at += kr[i] * sl[i]; }
    u[b * V_ + w] = au;
    t[b * V_ + w] = at;
}

__global__ void k_wkS(const float* __restrict__ Wk, const float* __restrict__ S,
                      float* __restrict__ T) {
    const int b = blockIdx.z;
    const int i0 = blockIdx.x * 64, j0 = blockIdx.y * 64;
    __shared__ float As[64][17];
    __shared__ float Bs[16][64];
    const int tid = threadIdx.x, tx = tid & 15, ty = tid >> 4;
    const int ar = tid >> 2, ac = (tid & 3) * 4;
    const int br = tid >> 4, bc = (tid & 15) * 4;
    float acc[4][4] = {};
    for (int k0 = 0; k0 < KQ_; k0 += 16) {
        const float4 a4 = *(const float4*)(Wk + (size_t)(i0 + ar) * KQ_ + k0 + ac);
        As[ar][ac + 0] = a4.x; As[ar][ac + 1] = a4.y;
        As[ar][ac + 2] = a4.z; As[ar][ac + 3] = a4.w;
        const float4 b4 = *(const float4*)(S + ((size_t)b * KQ_ + k0 + br) * KQ_ + j0 + bc);
        *(float4*)&Bs[br][bc] = b4;
        __syncthreads();
#pragma unroll
        for (int kk = 0; kk < 16; ++kk) {
            float ra[4], rb[4];
#pragma unroll
            for (int a = 0; a < 4; ++a) ra[a] = As[ty * 4 + a][kk];
#pragma unroll
            for (int q = 0; q < 4; ++q) rb[q] = Bs[kk][tx * 4 + q];
#pragma unroll
            for (int a = 0; a < 4; ++a)
#pragma unroll
                for (int q = 0; q < 4; ++q) acc[a][q] += ra[a] * rb[q];
        }
        __syncthreads();
    }
#pragma unroll
    for (int a = 0; a < 4; ++a) {
        float4 o; o.x = acc[a][0]; o.y = acc[a][1]; o.z = acc[a][2]; o.w = acc[a][3];
        *(float4*)(T + ((size_t)b * V_ + i0 + ty * 4 + a) * KQ_ + j0 + tx * 4) = o;
    }
}

__global__ void k_logits(const float* __restrict__ T, const float* __restrict__ Wq,
                         const float* __restrict__ bk, const float* __restrict__ bq,
                         const float* __restrict__ u, const float* __restrict__ t,
                         float* __restrict__ L) {
    const int b = blockIdx.z;
    const int i0 = blockIdx.x * 64, j0 = blockIdx.y * 64;
    __shared__ float As[64][17], Bs[64][17];
    const int tid = threadIdx.x, tx = tid & 15, ty = tid >> 4;
    const int r = tid >> 2, c = (tid & 3) * 4;
    float acc[4][4] = {};
    for (int k0 = 0; k0 < KQ_; k0 += 16) {
        const float4 a4 = *(const float4*)(T + ((size_t)b * V_ + i0 + r) * KQ_ + k0 + c);
        As[r][c + 0] = a4.x; As[r][c + 1] = a4.y; As[r][c + 2] = a4.z; As[r][c + 3] = a4.w;
        const float4 b4 = *(const float4*)(Wq + (size_t)(j0 + r) * KQ_ + k0 + c);
        Bs[r][c + 0] = b4.x; Bs[r][c + 1] = b4.y; Bs[r][c + 2] = b4.z; Bs[r][c + 3] = b4.w;
        __syncthreads();
#pragma unroll
        for (int kk = 0; kk < 16; ++kk) {
            float ra[4], rb[4];
#pragma unroll
            for (int a = 0; a < 4; ++a) ra[a] = As[ty * 4 + a][kk];
#pragma unroll
            for (int q = 0; q < 4; ++q) rb[q] = Bs[tx * 4 + q][kk];
#pragma unroll
            for (int a = 0; a < 4; ++a)
#pragma unroll
                for (int q = 0; q < 4; ++q) acc[a][q] += ra[a] * rb[q];
        }
        __syncthreads();
    }
#pragma unroll
    for (int a = 0; a < 4; ++a) {
        const int v = i0 + ty * 4 + a;
        const float bkv = bk[v];
        const float tv = t[b * V_ + v];
        float4 o;
        float* po = (float*)&o;
#pragma unroll
        for (int q = 0; q < 4; ++q) {
            const int w = j0 + tx * 4 + q;
            po[q] = acc[a][q] + bkv * (u[b * V_ + w] + 4096.0f * bq[w]) + tv * bq[w];
        }
        *(float4*)(L + ((size_t)b * V_ + v) * V_ + j0 + tx * 4) = o;
    }
}

__global__ void k_softmax(float* __restrict__ L) {
    const size_t row = blockIdx.x;
    float* p = L + row * V_;
    const int t = threadIdx.x;
    float vals[4];
    float m = -3.4e38f;
#pragma unroll
    for (int i = 0; i < 4; ++i) { vals[i] = p[t + i * 256]; m = fmaxf(m, vals[i]); }
    __shared__ float red[256];
    red[t] = m; __syncthreads();
    for (int s2 = 128; s2 > 0; s2 >>= 1) {
        if (t < s2) red[t] = fmaxf(red[t], red[t + s2]);
        __syncthreads();
    }
    m = red[0]; __syncthreads();
    float sum = 0.f;
#pragma unroll
    for (int i = 0; i < 4; ++i) { vals[i] = __expf(vals[i] - m); sum += vals[i]; }
    red[t] = sum; __syncthreads();
    for (int s2 = 128; s2 > 0; s2 >>= 1) {
        if (t < s2) red[t] += red[t + s2];
        __syncthreads();
    }
    const float inv = 1.f / red[0];
#pragma unroll
    for (int i = 0; i < 4; ++i) p[t + i * 256] = vals[i] * inv;
}

// generic 64x64 tiled transpose-cast: src fp32 [1024][1024] -> dst bf16 [1024][1024]^T
__global__ void k_transpose_cast(const float* __restrict__ src, u16* __restrict__ dst,
                                 size_t sbs, size_t dbs) {
    const float* s = src + (size_t)blockIdx.z * sbs;
    u16* d = dst + (size_t)blockIdx.z * dbs;
    __shared__ u16 tile[64][65];
    const int r0 = blockIdx.y * 64, c0 = blockIdx.x * 64;
    const int t = threadIdx.x;
#pragma unroll
    for (int rr = 0; rr < 16; ++rr) {
        const int row = rr * 4 + (t >> 6);
        tile[row][t & 63] = f2bf(s[(size_t)(r0 + row) * 1024 + c0 + (t & 63)]);
    }
    __syncthreads();
#pragma unroll
    for (int rr = 0; rr < 8; ++rr) {
        const int wrow = rr * 8 + (t >> 5);
        const int wc = (t & 31) * 2;
        ushort2 o; o.x = tile[wc][wrow]; o.y = tile[wc + 1][wrow];
        *(ushort2*)(d + (size_t)(c0 + wrow) * 1024 + r0 + wc) = o;
    }
}

// c_b[w] = sum_v attnT[b][w][v] * bv[v]  (one wave per row)
__global__ void k_cvec(const u16* __restrict__ attnT, const float* __restrict__ bv,
                       float* __restrict__ c) {
    const int b = blockIdx.x;
    const int w = blockIdx.y * 4 + (threadIdx.x >> 6);
    const int lane = threadIdx.x & 63;
    const u16* row = attnT + ((size_t)b * V_ + w) * V_;
    float acc = 0.f;
#pragma unroll
    for (int ch = 0; ch < 2; ++ch) {
        const int v0 = ch * 512 + lane * 8;
        const uint4 pk = *(const uint4*)(row + v0);
        const u32 ws[4] = {pk.x, pk.y, pk.z, pk.w};
#pragma unroll
        for (int q = 0; q < 4; ++q) {
            acc += bf2f((u16)(ws[q] & 0xffffu)) * bv[v0 + 2 * q];
            acc += bf2f((u16)(ws[q] >> 16)) * bv[v0 + 2 * q + 1];
        }
    }
    for (int off = 32; off; off >>= 1) acc += __shfl_down(acc, off);
    if (lane == 0) c[b * V_ + w] = acc;
}

// Ct[b][w][e] = sum_v attnT[b][w][v] * WvT[e][v]   (bf16 MFMA, 128x128 tile, BK=32)
__global__ void k_C_mfma(const u16* __restrict__ At, const u16* __restrict__ Bt,
                         u16* __restrict__ Ct) {
    const int b = blockIdx.z;
    const int m0 = blockIdx.y * 128, n0 = blockIdx.x * 128;
    const u16* Ab = At + (size_t)b * V_ * V_;
    __shared__ u16 As[128 * 32], Bs[128 * 32];
    const int tid = threadIdx.x, lane = tid & 63, wave = tid >> 6;
    const int wm = wave & 1, wn = wave >> 1;
    const int srow = tid >> 2, scol = (tid & 3) * 8;
    f32x4 acc[4][4] = {};
    for (int k0 = 0; k0 < V_; k0 += 32) {
        gl_lds16(Ab + (size_t)(m0 + srow) * V_ + k0 + scol, As + tid * 8);
        gl_lds16(Ab + (size_t)(m0 + 64 + srow) * V_ + k0 + scol, As + (256 + tid) * 8);
        gl_lds16(Bt + (size_t)(n0 + srow) * V_ + k0 + scol, Bs + tid * 8);
        gl_lds16(Bt + (size_t)(n0 + 64 + srow) * V_ + k0 + scol, Bs + (256 + tid) * 8);
        __syncthreads();
        bf16x8 af[4], bfr[4];
#pragma unroll
        for (int i = 0; i < 4; ++i)
            af[i] = *(const bf16x8*)(As + (wm * 64 + i * 16 + (lane & 15)) * 32 + (lane >> 4) * 8);
#pragma unroll
        for (int j = 0; j < 4; ++j)
            bfr[j] = *(const bf16x8*)(Bs + (wn * 64 + j * 16 + (lane & 15)) * 32 + (lane >> 4) * 8);
#pragma unroll
        for (int i = 0; i < 4; ++i)
#pragma unroll
            for (int j = 0; j < 4; ++j)
                acc[i][j] = __builtin_amdgcn_mfma_f32_16x16x32_bf16(af[i], bfr[j], acc[i][j], 0, 0, 0);
        __syncthreads();
    }
    u16* Cb = Ct + (size_t)b * V_ * V_;
    const int quad = lane >> 4, col = lane & 15;
#pragma unroll
    for (int i = 0; i < 4; ++i)
#pragma unroll
        for (int j = 0; j < 4; ++j)
#pragma unroll
            for (int r = 0; r < 4; ++r)
                Cb[(size_t)(m0 + wm * 64 + i * 16 + quad * 4 + r) * V_ +
                   n0 + wn * 64 + j * 16 + col] = f2bf(acc[i][j][r]);
}

// out[b][n][w] = gamma*(sum_e in[b][n][e]*Ct[b][w][e] + c[b][w]) + in[b][n][w]
// A staged fp32->bf16 in-kernel (perm pack); B via global_load_lds.
__global__ void k_out_mfma(const float* __restrict__ in, const u16* __restrict__ Ct,
                           const float* __restrict__ cvec, const float* __restrict__ gamma,
                           float* __restrict__ out) {
    const int id = blockIdx.x;
    // XCD swizzle: the 8 w-tiles sharing one A-tile land on ids == same (mod 8)
    const int agrp = ((id >> 6) << 3) | (id & 7);   // b*32 + ntile
    const int wtile = (id >> 3) & 7;
    const int b = agrp >> 5, ntile = agrp & 31;
    const int m0 = ntile * 128, n0 = wtile * 128;
    const float* Ain = in + (size_t)b * N_ * V_;
    const u16* Btb = Ct + (size_t)b * V_ * V_;
    __shared__ u16 As[128 * 32], Bs[128 * 32];
    const int tid = threadIdx.x, lane = tid & 63, wave = tid >> 6;
    const int wm = wave & 1, wn = wave >> 1;
    const int brow = tid >> 2, bcol = (tid & 3) * 8;
    const int arow = tid >> 3, acol = (tid & 7) * 4;
    f32x4 acc[4][4] = {};
    for (int k0 = 0; k0 < V_; k0 += 32) {
        gl_lds16(Btb + (size_t)(n0 + brow) * V_ + k0 + bcol, Bs + tid * 8);
        gl_lds16(Btb + (size_t)(n0 + 64 + brow) * V_ + k0 + bcol, Bs + (256 + tid) * 8);
#pragma unroll
        for (int ii = 0; ii < 4; ++ii) {
            const int row = arow + 32 * ii;
            const float4 v = *(const float4*)(Ain + (size_t)(m0 + row) * V_ + k0 + acol);
            const u32 ux = __builtin_bit_cast(u32, v.x) + 0x8000u;
            const u32 uy = __builtin_bit_cast(u32, v.y) + 0x8000u;
            const u32 uz = __builtin_bit_cast(u32, v.z) + 0x8000u;
            const u32 uw = __builtin_bit_cast(u32, v.w) + 0x8000u;
            uint2 p;
            p.x = __builtin_amdgcn_perm(uy, ux, 0x07060302u);
            p.y = __builtin_amdgcn_perm(uw, uz, 0x07060302u);
            *(uint2*)(As + row * 32 + acol) = p;
        }
        __syncthreads();
        bf16x8 af[4], bfr[4];
#pragma unroll
        for (int i = 0; i < 4; ++i)
            af[i] = *(const bf16x8*)(As + (wm * 64 + i * 16 + (lane & 15)) * 32 + (lane >> 4) * 8);
#pragma unroll
        for (int j = 0; j < 4; ++j)
            bfr[j] = *(const bf16x8*)(Bs + (wn * 64 + j * 16 + (lane & 15)) * 32 + (lane >> 4) * 8);
#pragma unroll
        for (int i = 0; i < 4; ++i)
#pragma unroll
            for (int j = 0; j < 4; ++j)
                acc[i][j] = __builtin_amdgcn_mfma_f32_16x16x32_bf16(af[i], bfr[j], acc[i][j], 0, 0, 0);
        __syncthreads();
    }
    const float g = gamma[0];
    const int quad = lane >> 4, col = lane & 15;
#pragma unroll
    for (int j = 0; j < 4; ++j) {
        const int n = n0 + wn * 64 + j * 16 + col;
        const float cv = cvec[b * V_ + n];
#pragma unroll
        for (int i = 0; i < 4; ++i) {
            const int mb = m0 + wm * 64 + i * 16 + quad * 4;
#pragma unroll
            for (int r = 0; r < 4; ++r) {
                const size_t off = (size_t)(b * N_ + mb + r) * V_ + n;
                out[off] = g * (acc[i][j][r] + cv) + in[off];
            }
        }
    }
}

extern "C" void kernel_launch(void* const* d_in, const int* in_sizes, int n_in,
                              void* d_out, int out_size, void* d_ws, size_t ws_size,
                              hipStream_t stream) {
    const float* in    = (const float*)d_in[0];
    const float* Wq    = (const float*)d_in[1];
    const float* bq    = (const float*)d_in[2];
    const float* Wk    = (const float*)d_in[3];
    const float* bk    = (const float*)d_in[4];
    const float* Wv    = (const float*)d_in[5];
    const float* bv    = (const float*)d_in[6];
    const float* gamma = (const float*)d_in[7];
    float* out = (float*)d_out;
    float* ws = (float*)d_ws;

    float* S   = ws + 0;
    u16*   WvT = (u16*)(ws + 0);          // aliases S (dead after k_wkS)
    float* sv  = ws + 524288;
    float* T   = ws + 526336;
    float* u   = ws + 2623488;
    float* tt  = ws + 2631680;
    float* L   = ws + 2639872;
    u16*   aT  = (u16*)(ws + 11028480);   // attnT bf16 [8][1024][1024]
    u16*   Ct  = (u16*)(ws + 15222784);   // Ct bf16 [8][1024][1024]
    float* cv  = ws + 19417088;

    hipMemsetAsync(S, 0, (size_t)(524288 + 2048) * sizeof(float), stream);

    k_sum_s  <<<dim3(8, 16),     256, 0, stream>>>(in, sv);
    k_syrk   <<<dim3(4, 4, 64),  256, 0, stream>>>(in, S);
    k_uv     <<<dim3(8, 4),      256, 0, stream>>>(Wq, Wk, sv, u, tt);
    k_wkS    <<<dim3(16, 4, 8),  256, 0, stream>>>(Wk, S, T);
    // S dead; write WvT over it
    k_transpose_cast<<<dim3(16, 16, 1), 256, 0, stream>>>(Wv, WvT, 0, 0);
    k_logits <<<dim3(16, 16, 8), 256, 0, stream>>>(T, Wq, bk, bq, u, tt, L);
    k_softmax<<<8192,            256, 0, stream>>>(L);
    k_transpose_cast<<<dim3(16, 16, 8), 256, 0, stream>>>(L, aT, (size_t)V_ * V_, (size_t)V_ * V_);
    k_cvec   <<<dim3(8, 256),    256, 0, stream>>>(aT, bv, cv);
    k_C_mfma <<<dim3(8, 8, 8),   256, 0, stream>>>(aT, WvT, Ct);
    k_out_mfma<<<2048,           256, 0, stream>>>(in, Ct, cv, gamma, out);
}